// Round 13
// baseline (277.203 us; speedup 1.0000x reference)
//
#include <hip/hip_runtime.h>
#include <hip/hip_bf16.h>

// SACRSN_v84 — v13: single fused kernel, 2 rows per block (4096 blocks).
// Halves weight/palette L2 traffic (every load feeds 2 rows), folds VQ in.
// All inner math verbatim from passing R8-R12; only thread mapping changed.

#define RSTRIDE 4736

static constexpr size_t OFF_VQLOSS = 38797312UL;  // 8192*4736
static constexpr size_t OFF_IDX    = 38805504UL;
static constexpr size_t OFF_SENT   = 38813696UL;
static constexpr size_t OFF_NENT   = 38813697UL;

struct Params {
  const float* curr_r; const float* curr_i;
  const float* mem_r;  const float* mem_i;
  const float* codebook;
  const float* qkv_Wr; const float* qkv_Wi; const float* qkv_br; const float* qkv_bi;
  const float* quad_Wr; const float* quad_Wi; const float* quad_br; const float* quad_bi;
  const float* sens_Wr; const float* sens_Wi; const float* sens_br; const float* sens_bi;
  const float* vis_pal; const float* aud_pal;
  const float* gate_W; const float* gate_b;
  const float* addr_W; const float* addr_b;
  const float* ln_gr; const float* ln_br; const float* ln_gi; const float* ln_bi;
  float* out;
  int* hist;          // ws: 128 ints
  float* rowent;      // ws + 512 B: 8192 floats
};

__global__ __launch_bounds__(256) void row2_kernel(Params P) {
  const int b = blockIdx.x;            // row pair index
  const int t = threadIdx.x;
  const int lane = t & 63;
  const int wv = t >> 6;

  __shared__ float zr[2][64], zi[2][64];
  __shared__ double s_pd[2][2][128];   // [half][row][code]
  __shared__ float s_qr[2][64], s_qi[2][64], s_kr[2][64], s_ki[2][64], s_vr[2][64], s_vi[2][64];
  __shared__ float sfl[2][128];
  __shared__ float s_sp[4][2][4][64];
  __shared__ float alg[2][32];
  __shared__ float s_eff[2][32];
  __shared__ float s_sim[2][32], s_attn[2][32];
  __shared__ float s_rr[2][4][8][8], s_ri[2][4][8][8];
  __shared__ float s_pv[2][4][32], s_pa[2][4][32];
  __shared__ float s_pvp[2][32], s_pap[2][32];
  __shared__ float s_vo[2][128], s_ao[2][128];
  __shared__ float s_wg[2], s_gate[2], s_vqls[2];
  __shared__ int s_idx[2];

  const size_t r0 = (size_t)b * 2;
  float* orow0 = P.out + r0 * RSTRIDE;
  float* orow1 = P.out + (r0 + 1) * RSTRIDE;

  // ---- A: issue mem loads (both rows) + stage z ----
  const int s = t >> 3, k = t & 7, d0 = k * 8;
  const float* mrp0 = P.mem_r + ((r0)     * 32 + s) * 64 + d0;
  const float* mip0 = P.mem_i + ((r0)     * 32 + s) * 64 + d0;
  const float* mrp1 = P.mem_r + ((r0 + 1) * 32 + s) * 64 + d0;
  const float* mip1 = P.mem_i + ((r0 + 1) * 32 + s) * 64 + d0;
  float4 a00 = *(const float4*)mrp0, a01 = *(const float4*)(mrp0 + 4);
  float4 b00 = *(const float4*)mip0, b01 = *(const float4*)(mip0 + 4);
  float4 a10 = *(const float4*)mrp1, a11 = *(const float4*)(mrp1 + 4);
  float4 b10 = *(const float4*)mip1, b11 = *(const float4*)(mip1 + 4);
  float mr0[8] = {a00.x, a00.y, a00.z, a00.w, a01.x, a01.y, a01.z, a01.w};
  float mi0[8] = {b00.x, b00.y, b00.z, b00.w, b01.x, b01.y, b01.z, b01.w};
  float mr1[8] = {a10.x, a10.y, a10.z, a10.w, a11.x, a11.y, a11.z, a11.w};
  float mi1[8] = {b10.x, b10.y, b10.z, b10.w, b11.x, b11.y, b11.z, b11.w};

  if (t < 128) zr[t >> 6][t & 63] = P.curr_r[r0 * 64 + t];
  else         zi[(t - 128) >> 6][t & 63] = P.curr_i[r0 * 64 + (t - 128)];
  __syncthreads();

  // ---- B: VQ f64 distance partials (codebook read once per block) ----
  {
    const int c = t & 127, h = t >> 7;
    const float* cb = P.codebook + (size_t)c * 128 + h * 64;
    const float* z0 = h ? zi[0] : zr[0];
    const float* z1 = h ? zi[1] : zr[1];
    double a0 = 0.0, a1 = 0.0;
    for (int x = 0; x < 64; ++x) {
      const double w = (double)cb[x];
      const double e0 = w - (double)z0[x]; a0 = fma(e0, e0, a0);
      const double e1 = w - (double)z1[x]; a1 = fma(e1, e1, a1);
    }
    s_pd[h][0][c] = a0;
    s_pd[h][1][c] = a1;
  }
  __syncthreads();

  // ---- C: argmin (waves 0,1) | wgate (wave 2) | addr logits (wave 3) ----
  if (wv < 2) {
    const int r = wv;
    double sv = s_pd[0][r][lane] + s_pd[1][r][lane]; int si = lane;
    const double dv = s_pd[0][r][lane + 64] + s_pd[1][r][lane + 64];
    if (dv < sv) { sv = dv; si = lane + 64; }
    #pragma unroll
    for (int m = 1; m <= 32; m <<= 1) {
      double ov = __shfl_xor(sv, m);
      int oi = __shfl_xor(si, m);
      if (ov < sv || (ov == sv && oi < si)) { sv = ov; si = oi; }
    }
    if (lane == 0) { s_idx[r] = si; atomicAdd(&P.hist[si], 1); }
  } else if (wv == 2) {
    const int r = lane >> 5, l = lane & 31;
    float wg = 0.f;
    #pragma unroll
    for (int q4 = 0; q4 < 4; ++q4) {
      const int jj = l + q4 * 32;
      const float z = (jj < 64) ? zr[r][jj] : zi[r][jj - 64];
      wg += z * P.gate_W[jj];
    }
    #pragma unroll
    for (int m = 16; m >= 1; m >>= 1) wg += __shfl_xor(wg, m);
    if (l == 0) s_wg[r] = wg;
  } else {
    const int r = lane >> 5, l = lane & 31;
    float a = P.addr_b[l];
    for (int d = 0; d < 64; ++d) a += zr[r][d] * P.addr_W[d * 32 + l];
    for (int d = 0; d < 64; ++d) a += zi[r][d] * P.addr_W[(64 + d) * 32 + l];
    alg[r][l] = a;
  }
  __syncthreads();

  // ---- D: sim partials (all) + clinears q/k/v/quad (wave=cl, both rows) + sens partials ----
  {
    float sp0 = 0.f, sp1 = 0.f;
    #pragma unroll
    for (int x = 0; x < 8; ++x) {
      sp0 += mr0[x] * zr[0][d0 + x] + mi0[x] * zi[0][d0 + x];
      sp1 += mr1[x] * zr[1][d0 + x] + mi1[x] * zi[1][d0 + x];
    }
    sp0 += __shfl_xor(sp0, 1); sp0 += __shfl_xor(sp0, 2); sp0 += __shfl_xor(sp0, 4);
    sp1 += __shfl_xor(sp1, 1); sp1 += __shfl_xor(sp1, 2); sp1 += __shfl_xor(sp1, 4);
    if (k == 0) { s_sim[0][s] = sp0; s_sim[1][s] = sp1; }
  }
  {
    const int j = lane, cl = wv;
    const float *Wr, *Wi, *br_, *bi_;
    if      (cl == 0) { Wr = P.qkv_Wr;        Wi = P.qkv_Wi;        br_ = P.qkv_br;       bi_ = P.qkv_bi;       }
    else if (cl == 1) { Wr = P.qkv_Wr + 4096; Wi = P.qkv_Wi + 4096; br_ = P.qkv_br + 64;  bi_ = P.qkv_bi + 64;  }
    else if (cl == 2) { Wr = P.qkv_Wr + 8192; Wi = P.qkv_Wi + 8192; br_ = P.qkv_br + 128; bi_ = P.qkv_bi + 128; }
    else              { Wr = P.quad_Wr;       Wi = P.quad_Wi;       br_ = P.quad_br;      bi_ = P.quad_bi;      }
    float aRR0 = 0.f, aRI0 = 0.f, aIR0 = 0.f, aII0 = 0.f;
    float aRR1 = 0.f, aRI1 = 0.f, aIR1 = 0.f, aII1 = 0.f;
    for (int d = 0; d < 64; ++d) {
      const float wr = Wr[d * 64 + j], wi = Wi[d * 64 + j];
      const float xr0 = zr[0][d], xi0 = zi[0][d];
      const float xr1 = zr[1][d], xi1 = zi[1][d];
      aRR0 += xr0 * wr; aRI0 += xr0 * wi; aIR0 += xi0 * wr; aII0 += xi0 * wi;
      aRR1 += xr1 * wr; aRI1 += xr1 * wi; aIR1 += xi1 * wr; aII1 += xi1 * wi;
    }
    const float brj = br_[j], bij = bi_[j];
    const float oR0 = (aRR0 + brj) - (aII0 + bij);
    const float oI0 = (aRI0 + bij) + (aIR0 + brj);
    const float oR1 = (aRR1 + brj) - (aII1 + bij);
    const float oI1 = (aRI1 + bij) + (aIR1 + brj);
    if      (cl == 0) { s_qr[0][j] = oR0; s_qi[0][j] = oI0; s_qr[1][j] = oR1; s_qi[1][j] = oI1; }
    else if (cl == 1) { s_kr[0][j] = oR0; s_ki[0][j] = oI0; s_kr[1][j] = oR1; s_ki[1][j] = oI1; }
    else if (cl == 2) { s_vr[0][j] = oR0; s_vi[0][j] = oI0; s_vr[1][j] = oR1; s_vi[1][j] = oI1; }
    else { orow0[512 + j] = -oI0; orow0[576 + j] = oR0;
           orow1[512 + j] = -oI1; orow1[576 + j] = oR1; }
    // sens split-K partials (quarter = wv), both rows
    float bRR0 = 0.f, bRI0 = 0.f, bIR0 = 0.f, bII0 = 0.f;
    float bRR1 = 0.f, bRI1 = 0.f, bIR1 = 0.f, bII1 = 0.f;
    for (int dd = 0; dd < 16; ++dd) {
      const int d = wv * 16 + dd;
      const float wr = P.sens_Wr[d * 64 + j], wi = P.sens_Wi[d * 64 + j];
      const float xr0 = zr[0][d], xi0 = zi[0][d];
      const float xr1 = zr[1][d], xi1 = zi[1][d];
      bRR0 += xr0 * wr; bRI0 += xr0 * wi; bIR0 += xi0 * wr; bII0 += xi0 * wi;
      bRR1 += xr1 * wr; bRI1 += xr1 * wi; bIR1 += xi1 * wr; bII1 += xi1 * wi;
    }
    s_sp[wv][0][0][j] = bRR0; s_sp[wv][0][1][j] = bRI0; s_sp[wv][0][2][j] = bIR0; s_sp[wv][0][3][j] = bII0;
    s_sp[wv][1][0][j] = bRR1; s_sp[wv][1][1][j] = bRI1; s_sp[wv][1][2][j] = bIR1; s_sp[wv][1][3][j] = bII1;
  }
  __syncthreads();

  // ---- E: sim softmax + vq_loss (w0) | addr softmax/top3/eff (w1) | sens combine + gate (w2,w3) ----
  if (wv == 0) {
    {
      const int r = lane >> 5, l = lane & 31;
      float v = s_sim[r][l];
      float mx = v;
      #pragma unroll
      for (int m = 16; m >= 1; m >>= 1) mx = fmaxf(mx, __shfl_xor(mx, m));
      float e = expf(v - mx);
      float sm = e;
      #pragma unroll
      for (int m = 16; m >= 1; m >>= 1) sm += __shfl_xor(sm, m);
      s_attn[r][l] = e / sm;
    }
    #pragma unroll
    for (int r2 = 0; r2 < 2; ++r2) {
      const float* cb = P.codebook + (size_t)s_idx[r2] * 128;
      const float d0_ = cb[lane] - zr[r2][lane];
      const float d1_ = cb[64 + lane] - zi[r2][lane];
      float v2 = d0_ * d0_ + d1_ * d1_;
      #pragma unroll
      for (int m = 1; m <= 32; m <<= 1) v2 += __shfl_xor(v2, m);
      if (lane == 0) s_vqls[r2] = 0.25f * v2 * (1.0f / 128.0f);
    }
  } else if (wv == 1) {
    const int r = lane >> 5, l = lane & 31;
    float lg = alg[r][l];
    float mx = lg;
    #pragma unroll
    for (int m = 16; m >= 1; m >>= 1) mx = fmaxf(mx, __shfl_xor(mx, m));
    float e = expf(lg - mx);
    float sm = e;
    #pragma unroll
    for (int m = 16; m >= 1; m >>= 1) sm += __shfl_xor(sm, m);
    const float w = e / sm;
    float es = -(w * logf(w + 1e-10f));
    #pragma unroll
    for (int m = 16; m >= 1; m >>= 1) es += __shfl_xor(es, m);
    if (l == 0) P.rowent[r0 + r] = es;
    // top-3 (lax.top_k: ties -> lower index), 32-lane group
    const float myw = w;
    bool picked = false;
    float val = w; int idx = l;
    float sumtop = 0.f;
    #pragma unroll
    for (int it = 0; it < 3; ++it) {
      float v2 = val; int i2 = idx;
      #pragma unroll
      for (int m = 16; m >= 1; m >>= 1) {
        float ov = __shfl_xor(v2, m); int oi = __shfl_xor(i2, m);
        if (ov > v2 || (ov == v2 && oi < i2)) { v2 = ov; i2 = oi; }
      }
      sumtop += v2;
      if (l == i2) { picked = true; val = -1e30f; }
    }
    const float wgate = 1.f / (1.f + expf(-(s_wg[r] + P.gate_b[0])));
    s_eff[r][l] = picked ? wgate * (myw / (sumtop + 1e-6f)) : 0.f;
  } else {
    const int r = wv - 2;
    const int j = lane;
    const float aRR = s_sp[0][r][0][j] + s_sp[1][r][0][j] + s_sp[2][r][0][j] + s_sp[3][r][0][j];
    const float aRI = s_sp[0][r][1][j] + s_sp[1][r][1][j] + s_sp[2][r][1][j] + s_sp[3][r][1][j];
    const float aIR = s_sp[0][r][2][j] + s_sp[1][r][2][j] + s_sp[2][r][2][j] + s_sp[3][r][2][j];
    const float aII = s_sp[0][r][3][j] + s_sp[1][r][3][j] + s_sp[2][r][3][j] + s_sp[3][r][3][j];
    const float oR = (aRR + P.sens_br[j]) - (aII + P.sens_bi[j]);
    const float oI = (aRI + P.sens_bi[j]) + (aIR + P.sens_br[j]);
    sfl[r][j] = oR; sfl[r][64 + j] = oI;
    if (lane < 32) {
      const int l = lane;
      float g = s_qr[r][l] * s_kr[r][l] + s_qi[r][l] * s_ki[r][l]
              + s_qr[r][l + 32] * s_kr[r][l + 32] + s_qi[r][l + 32] * s_ki[r][l + 32];
      #pragma unroll
      for (int m = 16; m >= 1; m >>= 1) g += __shfl_xor(g, m);
      if (l == 0) s_gate[r] = 1.f / (1.f + expf(-g));
    }
  }
  __syncthreads();

  // ---- F: read partials + tanh/LN (both rows) + palette partials ----
  {
    const float aw0 = s_attn[0][s], aw1 = s_attn[1][s];
    float pr[8], pi[8];
    #pragma unroll
    for (int x = 0; x < 8; ++x) { pr[x] = aw0 * mr0[x]; pi[x] = aw0 * mi0[x]; }
    #pragma unroll
    for (int m = 8; m <= 32; m <<= 1) {
      #pragma unroll
      for (int x = 0; x < 8; ++x) { pr[x] += __shfl_xor(pr[x], m); pi[x] += __shfl_xor(pi[x], m); }
    }
    if (lane < 8) {
      #pragma unroll
      for (int x = 0; x < 8; ++x) { s_rr[0][wv][lane][x] = pr[x]; s_ri[0][wv][lane][x] = pi[x]; }
    }
    #pragma unroll
    for (int x = 0; x < 8; ++x) { pr[x] = aw1 * mr1[x]; pi[x] = aw1 * mi1[x]; }
    #pragma unroll
    for (int m = 8; m <= 32; m <<= 1) {
      #pragma unroll
      for (int x = 0; x < 8; ++x) { pr[x] += __shfl_xor(pr[x], m); pi[x] += __shfl_xor(pi[x], m); }
    }
    if (lane < 8) {
      #pragma unroll
      for (int x = 0; x < 8; ++x) { s_rr[1][wv][lane][x] = pr[x]; s_ri[1][wv][lane][x] = pi[x]; }
    }
  }
  #pragma unroll
  for (int r = 0; r < 2; ++r) {
    const float eff = s_eff[r][s];
    const float* mrx = r ? mr1 : mr0;
    const float* mix = r ? mi1 : mi0;
    float* orow = r ? orow1 : orow0;
    float nr[8], ni[8];
    #pragma unroll
    for (int x = 0; x < 8; ++x) {
      nr[x] = tanhf(mrx[x] + eff * (zr[r][d0 + x] - mrx[x]));
      ni[x] = tanhf(mix[x] + eff * (zi[r][d0 + x] - mix[x]));
    }
    float sR = 0.f, sI = 0.f;
    #pragma unroll
    for (int x = 0; x < 8; ++x) { sR += nr[x]; sI += ni[x]; }
    sR += __shfl_xor(sR, 1); sR += __shfl_xor(sR, 2); sR += __shfl_xor(sR, 4);
    sI += __shfl_xor(sI, 1); sI += __shfl_xor(sI, 2); sI += __shfl_xor(sI, 4);
    const float mR = sR * (1.f / 64.f), mI = sI * (1.f / 64.f);
    float vR = 0.f, vI = 0.f;
    #pragma unroll
    for (int x = 0; x < 8; ++x) {
      const float dr = nr[x] - mR; vR += dr * dr;
      const float di = ni[x] - mI; vI += di * di;
    }
    vR += __shfl_xor(vR, 1); vR += __shfl_xor(vR, 2); vR += __shfl_xor(vR, 4);
    vI += __shfl_xor(vI, 1); vI += __shfl_xor(vI, 2); vI += __shfl_xor(vI, 4);
    const float invR = 1.f / sqrtf(vR * (1.f / 64.f) + 1e-6f);
    const float invI = 1.f / sqrtf(vI * (1.f / 64.f) + 1e-6f);
    float oR[8], oI[8];
    #pragma unroll
    for (int x = 0; x < 8; ++x) {
      const int d = d0 + x;
      oR[x] = (nr[x] - mR) * invR * P.ln_gr[d] + P.ln_br[d];
      oI[x] = (ni[x] - mI) * invI * P.ln_gi[d] + P.ln_bi[d];
    }
    *(float4*)&orow[640 + s * 64 + d0]      = make_float4(oR[0], oR[1], oR[2], oR[3]);
    *(float4*)&orow[640 + s * 64 + d0 + 4]  = make_float4(oR[4], oR[5], oR[6], oR[7]);
    *(float4*)&orow[2688 + s * 64 + d0]     = make_float4(oI[0], oI[1], oI[2], oI[3]);
    *(float4*)&orow[2688 + s * 64 + d0 + 4] = make_float4(oI[4], oI[5], oI[6], oI[7]);
  }
  {
    const float* sf = sfl[t >> 7];
    const int a = t & 31, q = (t >> 5) & 3;
    float sc = 0.f, sa = 0.f;
    for (int x = q * 32; x < q * 32 + 32; ++x) {
      sc += sf[x] * P.vis_pal[a * 128 + x];
      sa += sf[x] * P.aud_pal[a * 128 + x];
    }
    s_pv[t >> 7][q][a] = sc;
    s_pa[t >> 7][q][a] = sa;
  }
  __syncthreads();

  // ---- G: read combine (t<128) | vis softmax (w2) | aud softmax (w3) ----
  if (t < 128) {
    const int r = t >> 6, tt = t & 63, kk = tt >> 3, xx = tt & 7;
    const float rv = s_rr[r][0][kk][xx] + s_rr[r][1][kk][xx] + s_rr[r][2][kk][xx] + s_rr[r][3][kk][xx];
    const float iv = s_ri[r][0][kk][xx] + s_ri[r][1][kk][xx] + s_ri[r][2][kk][xx] + s_ri[r][3][kk][xx];
    float* orow = r ? orow1 : orow0;
    orow[256 + tt] = rv;
    orow[320 + tt] = iv;
  } else if (wv == 2) {
    const int r = lane >> 5, a = lane & 31;
    float sc = s_pv[r][0][a] + s_pv[r][1][a] + s_pv[r][2][a] + s_pv[r][3][a];
    float mx = sc;
    #pragma unroll
    for (int m = 16; m >= 1; m >>= 1) mx = fmaxf(mx, __shfl_xor(mx, m));
    float e = expf(sc - mx);
    float sm = e;
    #pragma unroll
    for (int m = 16; m >= 1; m >>= 1) sm += __shfl_xor(sm, m);
    s_pvp[r][a] = e / sm;
  } else {
    const int r = lane >> 5, a = lane & 31;
    float sc = s_pa[r][0][a] + s_pa[r][1][a] + s_pa[r][2][a] + s_pa[r][3][a];
    float mx = sc;
    #pragma unroll
    for (int m = 16; m >= 1; m >>= 1) mx = fmaxf(mx, __shfl_xor(mx, m));
    float e = expf(sc - mx);
    float sm = e;
    #pragma unroll
    for (int m = 16; m >= 1; m >>= 1) sm += __shfl_xor(sm, m);
    s_pap[r][a] = e / sm;
  }
  __syncthreads();

  // ---- H: palette attend-out + g writes ----
  {
    const int r = t >> 7, j = t & 127;
    float v = 0.f, w2 = 0.f;
    for (int a = 0; a < 32; ++a) {
      v  += s_pvp[r][a] * P.vis_pal[a * 128 + j];
      w2 += s_pap[r][a] * P.aud_pal[a * 128 + j];
    }
    s_vo[r][j] = v;
    s_ao[r][j] = w2;
    float* orow = r ? orow1 : orow0;
    if (j < 64) orow[128 + j] = s_vr[r][j] * s_gate[r];
    else        orow[192 + (j - 64)] = s_vi[r][j - 64] * s_gate[r];
  }
  __syncthreads();

  // ---- I: exp writes + vq writes + scalars ----
  {
    const int r = t >> 7, j = t & 127;
    float* orow = r ? orow1 : orow0;
    if (j < 64) orow[384 + j] = s_vo[r][j] - s_ao[r][64 + j];            // exp_r
    else        orow[448 + (j - 64)] = s_vo[r][j] + s_ao[r][j - 64];     // exp_i
    const float* cb = P.codebook + (size_t)s_idx[r] * 128;
    const float z = (j < 64) ? zr[r][j] : zi[r][j - 64];
    orow[j] = z + (cb[j] - z);                                           // straight-through
  }
  if (t < 2) {
    P.out[OFF_VQLOSS + r0 + t] = s_vqls[t];
    P.out[OFF_IDX + r0 + t] = (float)s_idx[t];
  }
}

__global__ __launch_bounds__(256) void finalize_k(const int* hist, const float* rowent,
                                                  float* out) {
  const int t = threadIdx.x;
  __shared__ float red[256];
  float se = 0.f;
  for (int i = t; i < 8192; i += 256) se += rowent[i];
  red[t] = se;
  __syncthreads();
  for (int off = 128; off >= 1; off >>= 1) {
    if (t < off) red[t] += red[t + off];
    __syncthreads();
  }
  if (t == 0) out[OFF_SENT] = red[0] / 8192.0f;
  __syncthreads();
  float ne = 0.f;
  if (t < 128) {
    const float pp = (float)hist[t] / 8192.0f;
    ne = -(pp * logf(pp + 1e-10f));
  }
  red[t] = ne;
  __syncthreads();
  for (int off = 128; off >= 1; off >>= 1) {
    if (t < off) red[t] += red[t + off];
    __syncthreads();
  }
  if (t == 0) out[OFF_NENT] = red[0] / logf(128.0f);
}

extern "C" void kernel_launch(void* const* d_in, const int* in_sizes, int n_in,
                              void* d_out, int out_size, void* d_ws, size_t ws_size,
                              hipStream_t stream) {
  (void)in_sizes; (void)n_in; (void)out_size; (void)ws_size;
  Params P;
  P.curr_r   = (const float*)d_in[0];
  P.curr_i   = (const float*)d_in[1];
  P.mem_r    = (const float*)d_in[2];
  P.mem_i    = (const float*)d_in[3];
  P.codebook = (const float*)d_in[4];
  P.qkv_Wr   = (const float*)d_in[5];
  P.qkv_Wi   = (const float*)d_in[6];
  P.qkv_br   = (const float*)d_in[7];
  P.qkv_bi   = (const float*)d_in[8];
  P.quad_Wr  = (const float*)d_in[9];
  P.quad_Wi  = (const float*)d_in[10];
  P.quad_br  = (const float*)d_in[11];
  P.quad_bi  = (const float*)d_in[12];
  P.sens_Wr  = (const float*)d_in[13];
  P.sens_Wi  = (const float*)d_in[14];
  P.sens_br  = (const float*)d_in[15];
  P.sens_bi  = (const float*)d_in[16];
  P.vis_pal  = (const float*)d_in[17];
  P.aud_pal  = (const float*)d_in[18];
  P.gate_W   = (const float*)d_in[19];
  P.gate_b   = (const float*)d_in[20];
  P.addr_W   = (const float*)d_in[21];
  P.addr_b   = (const float*)d_in[22];
  P.ln_gr    = (const float*)d_in[23];
  P.ln_br    = (const float*)d_in[24];
  P.ln_gi    = (const float*)d_in[25];
  P.ln_bi    = (const float*)d_in[26];
  P.out = (float*)d_out;
  P.hist = (int*)d_ws;
  P.rowent = (float*)((char*)d_ws + 512);

  hipMemsetAsync(d_ws, 0, 512, stream);
  row2_kernel<<<dim3(4096), dim3(256), 0, stream>>>(P);
  finalize_k<<<dim3(1), dim3(256), 0, stream>>>(P.hist, P.rowent, (float*)d_out);
}